// Round 8
// baseline (946.197 us; speedup 1.0000x reference)
//
#include <hip/hip_runtime.h>
#include <hip/hip_fp16.h>

// GCN encoder: 3x (GCNConv + ReLU), dims 256->128->64->32
// N=50000 nodes, E=800000 edges. edge_index delivered as int32 (harness).
// R2: CSR gather.  R5: fp16 H buffers.  R6: MFMA gemms.  R7: rank fill.
// R13: gemm2/gemm3 fused into agg1/agg2 epilogues (LDS-staged MFMA).
// R17: LDS-staged gemm1; "atomic wall" was GEMM1 (hist < 46us).
// R18: degree-sort perm hurt (-45us on aggs) -> reverted.
// R19: best recombination: fused hist+gemm1 (60us) + direct-order aggs.
// R20: back half (scanR->scanA->fill->agg1->agg2->agg3, 6 serial dispatches)
//      collapsed into ONE persistent kernel (GRID=768, guaranteed co-resident
//      via __launch_bounds__(256,4): VGPR<=128 -> >=4 blocks/CU >= 768 total)
//      with device-scope generation barriers. Removes 5 launch boundaries.
//      Phase math bit-identical to R19.

#define D0 256
#define D1 128
#define D2 64
#define D3 32

#define FIX_SCALE 16777216.0f           // 2^24 fixed-point for degree
#define FIX_INV   (1.0f / 16777216.0f)
#define GRID 768                        // persistent blocks (3/CU guaranteed)

typedef _Float16 half8 __attribute__((ext_vector_type(8)));
typedef float floatx4 __attribute__((ext_vector_type(4)));

struct GridBar { int cnt; int gen; };

// Device-wide generation barrier. All GRID blocks co-resident (see launch
// note). Release: __threadfence() flushes phase writes (agent-scope wb) before
// arrival; acquire load invalidates stale lines on the wait side.
__device__ __forceinline__ void grid_sync(GridBar* bar, int nblk, int g) {
    __syncthreads();
    if (threadIdx.x == 0) {
        __threadfence();
        int arrived = __hip_atomic_fetch_add(&bar->cnt, 1, __ATOMIC_ACQ_REL,
                                             __HIP_MEMORY_SCOPE_AGENT);
        if (arrived == nblk - 1) {
            __hip_atomic_store(&bar->cnt, 0, __ATOMIC_RELAXED,
                               __HIP_MEMORY_SCOPE_AGENT);
            __hip_atomic_store(&bar->gen, g + 1, __ATOMIC_RELEASE,
                               __HIP_MEMORY_SCOPE_AGENT);
        } else {
            while (__hip_atomic_load(&bar->gen, __ATOMIC_ACQUIRE,
                                     __HIP_MEMORY_SCOPE_AGENT) <= g) {
                __builtin_amdgcn_s_sleep(2);
            }
        }
    }
    __syncthreads();
}

// ------------------------------------ gemm1: LDS-staged A, persistent B ----
__device__ __forceinline__ void stage_slab(const float* __restrict__ X, int slab,
                                           _Float16 (*__restrict__ sA)[D0 + 8], int t) {
    const int row = t >> 4;
    const int c0 = (t & 15) * 16;
    const float* src = X + (size_t)(slab * 16 + row) * D0 + c0;
    float4 f0 = *(const float4*)(src + 0);
    float4 f1 = *(const float4*)(src + 4);
    float4 f2 = *(const float4*)(src + 8);
    float4 f3 = *(const float4*)(src + 12);
    half8 h0, h1;
    h0[0] = (_Float16)f0.x; h0[1] = (_Float16)f0.y;
    h0[2] = (_Float16)f0.z; h0[3] = (_Float16)f0.w;
    h0[4] = (_Float16)f1.x; h0[5] = (_Float16)f1.y;
    h0[6] = (_Float16)f1.z; h0[7] = (_Float16)f1.w;
    h1[0] = (_Float16)f2.x; h1[1] = (_Float16)f2.y;
    h1[2] = (_Float16)f2.z; h1[3] = (_Float16)f2.w;
    h1[4] = (_Float16)f3.x; h1[5] = (_Float16)f3.y;
    h1[6] = (_Float16)f3.z; h1[7] = (_Float16)f3.w;
    *(half8*)&sA[row][c0]     = h0;
    *(half8*)&sA[row][c0 + 8] = h1;
}

// ------------------------- fused hist + gemm1 (independent work) -----------
__global__ __launch_bounds__(256) void hist_gemm1_kernel(
        const float* __restrict__ x, const float* __restrict__ W1,
        _Float16* __restrict__ h1, int N,
        const int* __restrict__ ei, const float* __restrict__ ew,
        unsigned long long* __restrict__ pk, int* __restrict__ rank, int E,
        int gB) {
    __shared__ _Float16 sA[2][16][D0 + 8];
    const int b = blockIdx.x;
    if (b >= gB) {
        int e = (b - gB) * 256 + threadIdx.x;
        if (e < E) {
            int c = ei[E + e];
            unsigned int wfix = (unsigned int)(ew[e] * FIX_SCALE + 0.5f);
            unsigned long long old =
                atomicAdd(&pk[c], (1ULL << 32) | (unsigned long long)wfix);
            rank[e] = (int)(old >> 32);
        }
        return;
    }
    constexpr int NC = D0 / 32;
    const int tid = threadIdx.x;
    const int w = tid >> 6;
    const int lane = tid & 63;
    const int quad = lane >> 4;
    const int m = lane & 15;
    const int n0 = w * 32;

    half8 b0[NC], b1[NC];
#pragma unroll
    for (int c = 0; c < NC; ++c) {
#pragma unroll
        for (int j = 0; j < 8; ++j) {
            int k = c * 32 + quad * 8 + j;
            b0[c][j] = (_Float16)W1[(size_t)k * D1 + n0 + m];
            b1[c][j] = (_Float16)W1[(size_t)k * D1 + n0 + 16 + m];
        }
    }

    const int nslab = N >> 4;
    int slab = b;
    if (slab >= nslab) return;
    stage_slab(x, slab, sA[0], tid);
    __syncthreads();
    int buf = 0;
    while (true) {
        const int next = slab + gB;
        if (next < nslab) stage_slab(x, next, sA[buf ^ 1], tid);

        half8 a[NC];
#pragma unroll
        for (int c = 0; c < NC; ++c)
            a[c] = *(const half8*)&sA[buf][m][c * 32 + quad * 8];
        floatx4 acc0 = (floatx4){0.f, 0.f, 0.f, 0.f};
        floatx4 acc1 = (floatx4){0.f, 0.f, 0.f, 0.f};
#pragma unroll
        for (int c = 0; c < NC; ++c) {
            acc0 = __builtin_amdgcn_mfma_f32_16x16x32_f16(a[c], b0[c], acc0, 0, 0, 0);
            acc1 = __builtin_amdgcn_mfma_f32_16x16x32_f16(a[c], b1[c], acc1, 0, 0, 0);
        }

        const int r0 = slab * 16 + quad * 4;
#pragma unroll
        for (int r = 0; r < 4; ++r) {
            h1[(size_t)(r0 + r) * D1 + n0 + m]      = (_Float16)acc0[r];
            h1[(size_t)(r0 + r) * D1 + n0 + 16 + m] = (_Float16)acc1[r];
        }
        __syncthreads();
        if (next >= nslab) break;
        slab = next;
        buf ^= 1;
    }
}

// ------------------------------- mega phases (device functions) ------------
template <int DIN, int DOUT>
__device__ void agg_gemm_phase(char* smemRaw,
        const _Float16* __restrict__ H, const int* __restrict__ row_ptr,
        const int2* __restrict__ pairs, const float* __restrict__ dinv,
        const float* __restrict__ bias, const float* __restrict__ W,
        _Float16* __restrict__ Hout, int N) {
    constexpr int TPN = DIN / 8;
    constexpr int NPB = 256 / TPN;
    constexpr int NC  = DIN / 32;
    constexpr int S   = NPB / 16;
    constexpr int T   = DOUT / 16;
    static_assert(S * T == 4, "one tile per wave");
    _Float16 (*sA)[DIN + 8] = (_Float16 (*)[DIN + 8])smemRaw;

    const int tid = threadIdx.x;
    const int grp = tid / TPN;
    const int sl = tid % TPN;
    const int w = tid >> 6;
    const int lane = tid & 63;
    const int q = lane >> 4;
    const int m = lane & 15;
    const int s = w & (S - 1);
    const int t = w / S;

    // hoisted B-frags (same for every slab)
    half8 bf[NC];
#pragma unroll
    for (int c = 0; c < NC; ++c) {
#pragma unroll
        for (int j = 0; j < 8; ++j)
            bf[c][j] = (_Float16)W[(size_t)(c * 32 + q * 8 + j) * DOUT + t * 16 + m];
    }

    const int nvb = (N + NPB - 1) / NPB;
    for (int vb = blockIdx.x; vb < nvb; vb += gridDim.x) {
        const int node0 = vb * NPB;
        const int node = node0 + grp;
        const bool valid = node < N;

        float acc[8];
#pragma unroll
        for (int j = 0; j < 8; ++j) acc[j] = 0.0f;

        int beg = 0, end = 0;
        float di = 0.f;
        half8 uself = (half8){0,0,0,0,0,0,0,0};
        float bb[8];
        if (valid) {
            beg = row_ptr[node];
            end = row_ptr[node + 1];
            di = dinv[node];
            uself = *(const half8*)&H[(size_t)node * DIN + sl * 8];
            *(float4*)&bb[0] = *(const float4*)&bias[sl * 8];
            *(float4*)&bb[4] = *(const float4*)&bias[sl * 8 + 4];
        }

        if (end > beg) {
            const int last = end - 1;
            int2 p0 = pairs[beg];
            int2 p1 = pairs[min(beg + 1, last)];
            int2 p2 = pairs[min(beg + 2, last)];
            int2 p3 = pairs[min(beg + 3, last)];
            int2 p4 = pairs[min(beg + 4, last)];
            half8 u0 = *(const half8*)&H[(size_t)p0.x * DIN + sl * 8];
            half8 u1 = *(const half8*)&H[(size_t)p1.x * DIN + sl * 8];
            half8 u2 = *(const half8*)&H[(size_t)p2.x * DIN + sl * 8];
            half8 u3 = *(const half8*)&H[(size_t)p3.x * DIN + sl * 8];
            for (int k = beg; k < end; ++k) {
                int2 p5 = pairs[min(k + 5, last)];
                half8 u4 = *(const half8*)&H[(size_t)p4.x * DIN + sl * 8];
                float wv = __int_as_float(p0.y);
#pragma unroll
                for (int j = 0; j < 8; ++j) acc[j] = fmaf(wv, (float)u0[j], acc[j]);
                p0 = p1; p1 = p2; p2 = p3; p3 = p4; p4 = p5;
                u0 = u1; u1 = u2; u2 = u3; u3 = u4;
            }
        }

        if (valid) {
            float d2 = di * di;
#pragma unroll
            for (int j = 0; j < 8; ++j) acc[j] = fmaf(d2, (float)uself[j], acc[j]);
            half8 o;
#pragma unroll
            for (int j = 0; j < 8; ++j) o[j] = (_Float16)fmaxf(acc[j] + bb[j], 0.f);
            *(half8*)&sA[grp][sl * 8] = o;
        }
        __syncthreads();

        half8 a[NC];
#pragma unroll
        for (int c = 0; c < NC; ++c)
            a[c] = *(const half8*)&sA[s * 16 + m][c * 32 + q * 8];
        floatx4 o4 = (floatx4){0.f, 0.f, 0.f, 0.f};
#pragma unroll
        for (int c = 0; c < NC; ++c)
            o4 = __builtin_amdgcn_mfma_f32_16x16x32_f16(a[c], bf[c], o4, 0, 0, 0);
#pragma unroll
        for (int r = 0; r < 4; ++r) {
            const int nr = node0 + s * 16 + q * 4 + r;
            if (nr < N) Hout[(size_t)nr * DOUT + t * 16 + m] = (_Float16)o4[r];
        }
        __syncthreads();   // sA reused next vb
    }
}

__device__ void agg_final_phase(const _Float16* __restrict__ H,
        const int* __restrict__ row_ptr, const int2* __restrict__ pairs,
        const float* __restrict__ dinv, const float* __restrict__ bias,
        float* __restrict__ out, int N) {
    constexpr int D = D3;
    constexpr int TPN = D / 8;        // 4
    constexpr int NPB = 256 / TPN;    // 64
    const int tid = threadIdx.x;
    const int grp = tid / TPN;
    const int lane = tid % TPN;
    const int nvb = (N + NPB - 1) / NPB;
    for (int vb = blockIdx.x; vb < nvb; vb += gridDim.x) {
        const int node = vb * NPB + grp;
        if (node >= N) continue;

        const int beg = row_ptr[node];
        const int end = row_ptr[node + 1];
        const float di = dinv[node];
        const half8 uself = *(const half8*)&H[(size_t)node * D + lane * 8];
        float b[8];
        *(float4*)&b[0] = *(const float4*)&bias[lane * 8];
        *(float4*)&b[4] = *(const float4*)&bias[lane * 8 + 4];

        float acc[8];
#pragma unroll
        for (int j = 0; j < 8; ++j) acc[j] = 0.0f;

        if (end > beg) {
            const int last = end - 1;
            int2 p0 = pairs[beg];
            int2 p1 = pairs[min(beg + 1, last)];
            int2 p2 = pairs[min(beg + 2, last)];
            int2 p3 = pairs[min(beg + 3, last)];
            int2 p4 = pairs[min(beg + 4, last)];
            half8 u0 = *(const half8*)&H[(size_t)p0.x * D + lane * 8];
            half8 u1 = *(const half8*)&H[(size_t)p1.x * D + lane * 8];
            half8 u2 = *(const half8*)&H[(size_t)p2.x * D + lane * 8];
            half8 u3 = *(const half8*)&H[(size_t)p3.x * D + lane * 8];
            for (int k = beg; k < end; ++k) {
                int2 p5 = pairs[min(k + 5, last)];
                half8 u4 = *(const half8*)&H[(size_t)p4.x * D + lane * 8];
                float w = __int_as_float(p0.y);
#pragma unroll
                for (int j = 0; j < 8; ++j) acc[j] = fmaf(w, (float)u0[j], acc[j]);
                p0 = p1; p1 = p2; p2 = p3; p3 = p4; p4 = p5;
                u0 = u1; u1 = u2; u2 = u3; u3 = u4;
            }
        }
        const float d2 = di * di;
#pragma unroll
        for (int j = 0; j < 8; ++j) acc[j] = fmaf(d2, (float)uself[j], acc[j]);
#pragma unroll
        for (int j = 0; j < 8; ++j) acc[j] = fmaxf(acc[j] + b[j], 0.f);

        float* dst = &out[(size_t)node * D + lane * 8];
        *(float4*)&dst[0] = make_float4(acc[0], acc[1], acc[2], acc[3]);
        *(float4*)&dst[4] = make_float4(acc[4], acc[5], acc[6], acc[7]);
    }
}

// ----------------- mega: scanR | scanA | fill | agg1 | agg2 | agg3 ---------
__global__ __launch_bounds__(256, 4) void mega_kernel(
        const unsigned long long* __restrict__ pk,
        float* __restrict__ dinv, int* __restrict__ cnt,
        int* __restrict__ row_ptr, int* __restrict__ bsum,
        const int* __restrict__ ei, const float* __restrict__ ew,
        const int* __restrict__ rank, int2* __restrict__ pairs,
        const _Float16* __restrict__ h1,
        const float* __restrict__ b1, const float* __restrict__ W2,
        _Float16* __restrict__ h2,
        const float* __restrict__ b2, const float* __restrict__ W3,
        _Float16* __restrict__ h3,
        const float* __restrict__ b3, float* __restrict__ out,
        GridBar* bar, int N, int E, int scanB) {
    __shared__ __align__(16) char smem[4608];
    const int t = threadIdx.x;
    const int nblk = gridDim.x;

    // ---- phase 1: scan_reduce ----
    {
        int* s = (int*)smem;
        for (int vb = blockIdx.x; vb < scanB; vb += nblk) {
            const int i = vb * 256 + t;
            int v = 0;
            if (i < N) {
                unsigned long long p = pk[i];
                float d = (float)(unsigned int)(p & 0xffffffffULL) * FIX_INV + 1.0f;
                dinv[i] = rsqrtf(d);
                v = (int)(p >> 32);
                cnt[i] = v;
            }
            s[t] = v;
            __syncthreads();
#pragma unroll
            for (int off = 128; off > 0; off >>= 1) {
                if (t < off) s[t] += s[t + off];
                __syncthreads();
            }
            if (t == 0) bsum[vb] = s[0];
            __syncthreads();
        }
    }
    grid_sync(bar, nblk, 0);

    // ---- phase 2: scan_apply ----
    {
        int* bs = (int*)smem;
        int* s = (int*)smem + 256;
        for (int vb = blockIdx.x; vb < scanB; vb += nblk) {
            bs[t] = (t < scanB) ? bsum[t] : 0;
            __syncthreads();
#pragma unroll
            for (int off = 1; off < 256; off <<= 1) {
                int u = (t >= off) ? bs[t - off] : 0;
                __syncthreads();
                bs[t] += u;
                __syncthreads();
            }
            const int myOff = (vb > 0) ? bs[vb - 1] : 0;
            const int i = vb * 256 + t;
            const int v = (i < N) ? cnt[i] : 0;
            s[t] = v;
            __syncthreads();
#pragma unroll
            for (int off = 1; off < 256; off <<= 1) {
                int u = (t >= off) ? s[t - off] : 0;
                __syncthreads();
                s[t] += u;
                __syncthreads();
            }
            if (i < N) row_ptr[i] = s[t] - v + myOff;
            if (vb == 0 && t == 0) row_ptr[N] = bs[scanB - 1];
            __syncthreads();
        }
    }
    grid_sync(bar, nblk, 1);

    // ---- phase 3: fill ----
    for (int e = blockIdx.x * 256 + t; e < E; e += nblk * 256) {
        int r = ei[e];
        int c = ei[E + e];
        float w = dinv[r] * ew[e] * dinv[c];
        pairs[row_ptr[c] + rank[e]] = make_int2(r, __float_as_int(w));
    }
    grid_sync(bar, nblk, 2);

    // ---- phase 4: agg1 (+gemm2) ----
    agg_gemm_phase<D1, D2>(smem, h1, row_ptr, pairs, dinv, b1, W2, h2, N);
    grid_sync(bar, nblk, 3);

    // ---- phase 5: agg2 (+gemm3) ----
    agg_gemm_phase<D2, D3>(smem, h2, row_ptr, pairs, dinv, b2, W3, h3, N);
    grid_sync(bar, nblk, 4);

    // ---- phase 6: agg3 + epilogue ----
    agg_final_phase(h3, row_ptr, pairs, dinv, b3, out, N);
}

// ---------------------------------------------------------------- launch ----
extern "C" void kernel_launch(void* const* d_in, const int* in_sizes, int n_in,
                              void* d_out, int out_size, void* d_ws, size_t ws_size,
                              hipStream_t stream) {
    const float* x   = (const float*)d_in[0];
    const int* ei    = (const int*)d_in[1];
    const float* ew  = (const float*)d_in[2];
    const float* W1  = (const float*)d_in[3];
    const float* b1  = (const float*)d_in[4];
    const float* W2  = (const float*)d_in[5];
    const float* b2  = (const float*)d_in[6];
    const float* W3  = (const float*)d_in[7];
    const float* b3  = (const float*)d_in[8];
    float* out = (float*)d_out;

    const int N = in_sizes[0] / D0;   // 50000
    const int E = in_sizes[2];        // 800000
    (void)n_in; (void)out_size; (void)ws_size;

    // ---- workspace carving ----
    char* ws = (char*)d_ws;
    size_t off = 0;
    auto carve = [&](size_t bytes) -> void* {
        void* p = (void*)(ws + off);
        off += (bytes + 255) & ~(size_t)255;
        return p;
    };
    const size_t pkBytes = ((size_t)N * 8 + 255) & ~(size_t)255;
    unsigned long long* pk = (unsigned long long*)carve((size_t)N * 8);
    GridBar* bar   = (GridBar*)carve(256);          // contiguous after pk
    float* dinv    = (float*)carve((size_t)N * 4);
    int*   cnt     = (int*)carve((size_t)N * 4);
    int*   row_ptr = (int*)carve((size_t)(N + 1) * 4);
    int*   rank    = (int*)carve((size_t)E * 4);
    int*   bsum    = (int*)carve(256 * 4);
    int2*  pairs   = (int2*)carve((size_t)E * 8);
    _Float16* bufH = (_Float16*)carve((size_t)N * D1 * 2);
    _Float16* bufO = (_Float16*)carve((size_t)N * D1 * 2);

    _Float16* h1 = bufH;              // N x 128 fp16 (gemm1 out)
    _Float16* h2 = bufO;              // N x 64  fp16 (agg1+gemm2 out)
    _Float16* h3 = bufH;              // N x 32  fp16 (agg2+gemm3 out; h1 dead)

    const int eb = (E + 255) / 256;       // 3125
    const int scanB = (N + 255) / 256;    // 196 (must be <= 256)
    const int gB = 768;                   // gemm1 blocks

    // ---- zero pk + barrier in ONE memset (contiguous) ----
    hipMemsetAsync(pk, 0, pkBytes + 256, stream);

    // ---- fused: hist + gemm1 (independent work, one dispatch) ----
    hist_gemm1_kernel<<<gB + eb, 256, 0, stream>>>(
        x, W1, h1, N, ei, ew, pk, rank, E, gB);

    // ---- everything else: one persistent kernel, 5 device barriers ----
    mega_kernel<<<GRID, 256, 0, stream>>>(
        pk, dinv, cnt, row_ptr, bsum, ei, ew, rank, pairs,
        h1, b1, W2, h2, b2, W3, h3, b3, out,
        bar, N, E, scanB);
}

// Round 9
// 242.844 us; speedup vs baseline: 3.8963x; 3.8963x over previous
//
#include <hip/hip_runtime.h>
#include <hip/hip_fp16.h>

// GCN encoder: 3x (GCNConv + ReLU), dims 256->128->64->32
// N=50000 nodes, E=800000 edges. edge_index delivered as int32 (harness).
// R2: CSR gather.  R5: fp16 H buffers.  R6: MFMA gemms.  R7: rank fill.
// R13: gemm2/gemm3 fused into agg epilogues (LDS-staged MFMA).
// R17: LDS-staged gemm1; "atomic wall" was GEMM1 (hist < 46us).
// R18: degree-sort perm hurt -> reverted.  R19: best combo, 248.4us.
// R20: persistent mega-kernel FAILED (826us): __launch_bounds__(256,4)
//      squeezed VGPR to 44 -> gather pipeline serialized/spilled. Reverted.
// R21: aggs show ~constant edge rate (17-20 G/s) while TLP halves per layer
//      (agg1 800K threads, agg2 400K, agg3 200K) -> TLP-starved latency
//      theory. Edge-split: agg2 = 2 subs x 8 lanes/node, agg3 = 4 subs x 4
//      lanes/node (all aggs now 800K threads); partials combined in LDS.
//      agg1 + everything else byte-identical to R19.

#define D0 256
#define D1 128
#define D2 64
#define D3 32

#define FIX_SCALE 16777216.0f           // 2^24 fixed-point for degree
#define FIX_INV   (1.0f / 16777216.0f)

typedef _Float16 half8 __attribute__((ext_vector_type(8)));
typedef float floatx4 __attribute__((ext_vector_type(4)));

// ------------------------------------ gemm1: LDS-staged A, persistent B ----
__device__ __forceinline__ void stage_slab(const float* __restrict__ X, int slab,
                                           _Float16 (*__restrict__ sA)[D0 + 8], int t) {
    const int row = t >> 4;
    const int c0 = (t & 15) * 16;
    const float* src = X + (size_t)(slab * 16 + row) * D0 + c0;
    float4 f0 = *(const float4*)(src + 0);
    float4 f1 = *(const float4*)(src + 4);
    float4 f2 = *(const float4*)(src + 8);
    float4 f3 = *(const float4*)(src + 12);
    half8 h0, h1;
    h0[0] = (_Float16)f0.x; h0[1] = (_Float16)f0.y;
    h0[2] = (_Float16)f0.z; h0[3] = (_Float16)f0.w;
    h0[4] = (_Float16)f1.x; h0[5] = (_Float16)f1.y;
    h0[6] = (_Float16)f1.z; h0[7] = (_Float16)f1.w;
    h1[0] = (_Float16)f2.x; h1[1] = (_Float16)f2.y;
    h1[2] = (_Float16)f2.z; h1[3] = (_Float16)f2.w;
    h1[4] = (_Float16)f3.x; h1[5] = (_Float16)f3.y;
    h1[6] = (_Float16)f3.z; h1[7] = (_Float16)f3.w;
    *(half8*)&sA[row][c0]     = h0;
    *(half8*)&sA[row][c0 + 8] = h1;
}

// ------------------------- fused hist + gemm1 (independent work) -----------
__global__ __launch_bounds__(256) void hist_gemm1_kernel(
        const float* __restrict__ x, const float* __restrict__ W1,
        _Float16* __restrict__ h1, int N,
        const int* __restrict__ ei, const float* __restrict__ ew,
        unsigned long long* __restrict__ pk, int* __restrict__ rank, int E,
        int gB) {
    __shared__ _Float16 sA[2][16][D0 + 8];
    const int b = blockIdx.x;
    if (b >= gB) {
        int e = (b - gB) * 256 + threadIdx.x;
        if (e < E) {
            int c = ei[E + e];
            unsigned int wfix = (unsigned int)(ew[e] * FIX_SCALE + 0.5f);
            unsigned long long old =
                atomicAdd(&pk[c], (1ULL << 32) | (unsigned long long)wfix);
            rank[e] = (int)(old >> 32);
        }
        return;
    }
    constexpr int NC = D0 / 32;
    const int tid = threadIdx.x;
    const int w = tid >> 6;
    const int lane = tid & 63;
    const int quad = lane >> 4;
    const int m = lane & 15;
    const int n0 = w * 32;

    half8 b0[NC], b1[NC];
#pragma unroll
    for (int c = 0; c < NC; ++c) {
#pragma unroll
        for (int j = 0; j < 8; ++j) {
            int k = c * 32 + quad * 8 + j;
            b0[c][j] = (_Float16)W1[(size_t)k * D1 + n0 + m];
            b1[c][j] = (_Float16)W1[(size_t)k * D1 + n0 + 16 + m];
        }
    }

    const int nslab = N >> 4;
    int slab = b;
    if (slab >= nslab) return;
    stage_slab(x, slab, sA[0], tid);
    __syncthreads();
    int buf = 0;
    while (true) {
        const int next = slab + gB;
        if (next < nslab) stage_slab(x, next, sA[buf ^ 1], tid);

        half8 a[NC];
#pragma unroll
        for (int c = 0; c < NC; ++c)
            a[c] = *(const half8*)&sA[buf][m][c * 32 + quad * 8];
        floatx4 acc0 = (floatx4){0.f, 0.f, 0.f, 0.f};
        floatx4 acc1 = (floatx4){0.f, 0.f, 0.f, 0.f};
#pragma unroll
        for (int c = 0; c < NC; ++c) {
            acc0 = __builtin_amdgcn_mfma_f32_16x16x32_f16(a[c], b0[c], acc0, 0, 0, 0);
            acc1 = __builtin_amdgcn_mfma_f32_16x16x32_f16(a[c], b1[c], acc1, 0, 0, 0);
        }

        const int r0 = slab * 16 + quad * 4;
#pragma unroll
        for (int r = 0; r < 4; ++r) {
            h1[(size_t)(r0 + r) * D1 + n0 + m]      = (_Float16)acc0[r];
            h1[(size_t)(r0 + r) * D1 + n0 + 16 + m] = (_Float16)acc1[r];
        }
        __syncthreads();
        if (next >= nslab) break;
        slab = next;
        buf ^= 1;
    }
}

// --------------------------------------------- 2-phase exclusive scan ------
__global__ __launch_bounds__(256) void scan_reduce(const unsigned long long* __restrict__ pk,
                                                   float* __restrict__ dinv,
                                                   int* __restrict__ cnt,
                                                   int* __restrict__ blockSum, int N) {
    __shared__ int s[256];
    const int t = threadIdx.x;
    const int i = blockIdx.x * 256 + t;
    int v = 0;
    if (i < N) {
        unsigned long long p = pk[i];
        float d = (float)(unsigned int)(p & 0xffffffffULL) * FIX_INV + 1.0f;  // +1 self-loop
        dinv[i] = rsqrtf(d);
        v = (int)(p >> 32);
        cnt[i] = v;
    }
    s[t] = v;
    __syncthreads();
#pragma unroll
    for (int off = 128; off > 0; off >>= 1) {
        if (t < off) s[t] += s[t + off];
        __syncthreads();
    }
    if (t == 0) blockSum[blockIdx.x] = s[0];
}

__global__ __launch_bounds__(256) void scan_apply(const int* __restrict__ cnt,
                                                  const int* __restrict__ blockSum,
                                                  int* __restrict__ row_ptr, int N, int B) {
    __shared__ int bs[256];
    __shared__ int s[256];
    const int t = threadIdx.x;
    bs[t] = (t < B) ? blockSum[t] : 0;
    __syncthreads();
#pragma unroll
    for (int off = 1; off < 256; off <<= 1) {
        int u = (t >= off) ? bs[t - off] : 0;
        __syncthreads();
        bs[t] += u;
        __syncthreads();
    }
    const int myOff = (blockIdx.x > 0) ? bs[blockIdx.x - 1] : 0;
    const int i = blockIdx.x * 256 + t;
    const int v = (i < N) ? cnt[i] : 0;
    s[t] = v;
    __syncthreads();
#pragma unroll
    for (int off = 1; off < 256; off <<= 1) {
        int u = (t >= off) ? s[t - off] : 0;
        __syncthreads();
        s[t] += u;
        __syncthreads();
    }
    if (i < N) row_ptr[i] = s[t] - v + myOff;
    if (blockIdx.x == 0 && t == 0) row_ptr[N] = bs[B - 1];
}

// ------------------------------------------------- bucket fill (CSR) -------
__global__ void fill_kernel(const int* __restrict__ ei, const float* __restrict__ ew,
                            const float* __restrict__ dinv,
                            const int* __restrict__ row_ptr, const int* __restrict__ rank,
                            int2* __restrict__ pairs, int E) {
    int e = blockIdx.x * blockDim.x + threadIdx.x;
    if (e < E) {
        int r = ei[e];
        int c = ei[E + e];
        float w = dinv[r] * ew[e] * dinv[c];
        pairs[row_ptr[c] + rank[e]] = make_int2(r, __float_as_int(w));
    }
}

// ---------------------- layer-1 aggregate + gemm2 (unchanged, R19) ---------
template <int DIN, int DOUT>
__global__ __launch_bounds__(256) void agg_gemm_kernel(
        const _Float16* __restrict__ H, const int* __restrict__ row_ptr,
        const int2* __restrict__ pairs, const float* __restrict__ dinv,
        const float* __restrict__ bias, const float* __restrict__ W,
        _Float16* __restrict__ Hout, int N) {
    constexpr int TPN = DIN / 8;
    constexpr int NPB = 256 / TPN;
    constexpr int NC  = DIN / 32;
    constexpr int S   = NPB / 16;
    constexpr int T   = DOUT / 16;
    static_assert(S * T == 4, "one tile per wave");
    __shared__ _Float16 sA[NPB][DIN + 8];

    const int tid = threadIdx.x;
    const int g = tid / TPN;
    const int sl = tid % TPN;
    const int node0 = blockIdx.x * NPB;
    const int node = node0 + g;
    const bool valid = node < N;

    const int w = tid >> 6;
    const int lane = tid & 63;
    const int q = lane >> 4;
    const int m = lane & 15;
    const int s = w & (S - 1);
    const int t = w / S;
    half8 bf[NC];
#pragma unroll
    for (int c = 0; c < NC; ++c) {
#pragma unroll
        for (int j = 0; j < 8; ++j)
            bf[c][j] = (_Float16)W[(size_t)(c * 32 + q * 8 + j) * DOUT + t * 16 + m];
    }

    float acc[8];
#pragma unroll
    for (int j = 0; j < 8; ++j) acc[j] = 0.0f;

    int beg = 0, end = 0;
    float di = 0.f;
    half8 uself = (half8){0,0,0,0,0,0,0,0};
    float bb[8];
    if (valid) {
        beg = row_ptr[node];
        end = row_ptr[node + 1];
        di = dinv[node];
        uself = *(const half8*)&H[(size_t)node * DIN + sl * 8];
        *(float4*)&bb[0] = *(const float4*)&bias[sl * 8];
        *(float4*)&bb[4] = *(const float4*)&bias[sl * 8 + 4];
    }

    if (end > beg) {
        const int last = end - 1;
        int2 p0 = pairs[beg];
        int2 p1 = pairs[min(beg + 1, last)];
        int2 p2 = pairs[min(beg + 2, last)];
        int2 p3 = pairs[min(beg + 3, last)];
        int2 p4 = pairs[min(beg + 4, last)];
        half8 u0 = *(const half8*)&H[(size_t)p0.x * DIN + sl * 8];
        half8 u1 = *(const half8*)&H[(size_t)p1.x * DIN + sl * 8];
        half8 u2 = *(const half8*)&H[(size_t)p2.x * DIN + sl * 8];
        half8 u3 = *(const half8*)&H[(size_t)p3.x * DIN + sl * 8];
        for (int k = beg; k < end; ++k) {
            int2 p5 = pairs[min(k + 5, last)];
            half8 u4 = *(const half8*)&H[(size_t)p4.x * DIN + sl * 8];
            float wv = __int_as_float(p0.y);
#pragma unroll
            for (int j = 0; j < 8; ++j) acc[j] = fmaf(wv, (float)u0[j], acc[j]);
            p0 = p1; p1 = p2; p2 = p3; p3 = p4; p4 = p5;
            u0 = u1; u1 = u2; u2 = u3; u3 = u4;
        }
    }

    if (valid) {
        float d2 = di * di;
#pragma unroll
        for (int j = 0; j < 8; ++j) acc[j] = fmaf(d2, (float)uself[j], acc[j]);
        half8 o;
#pragma unroll
        for (int j = 0; j < 8; ++j) o[j] = (_Float16)fmaxf(acc[j] + bb[j], 0.f);
        *(half8*)&sA[g][sl * 8] = o;
    }
    __syncthreads();

    half8 a[NC];
#pragma unroll
    for (int c = 0; c < NC; ++c)
        a[c] = *(const half8*)&sA[s * 16 + m][c * 32 + q * 8];
    floatx4 o4 = (floatx4){0.f, 0.f, 0.f, 0.f};
#pragma unroll
    for (int c = 0; c < NC; ++c)
        o4 = __builtin_amdgcn_mfma_f32_16x16x32_f16(a[c], bf[c], o4, 0, 0, 0);
#pragma unroll
    for (int r = 0; r < 4; ++r) {
        const int nr = node0 + s * 16 + q * 4 + r;
        if (nr < N) Hout[(size_t)nr * DOUT + t * 16 + m] = (_Float16)o4[r];
    }
}

// ------------- layer-2 aggregate + gemm3, edge-split x2 (R21) --------------
// 16 threads/node: sub = bit3 (edge parity), sl = bits0-2 (8 cols x 8).
// 16 nodes/block, 3125 blocks -> 800K gather threads (TLP = agg1).
__global__ __launch_bounds__(256) void agg2_split_kernel(
        const _Float16* __restrict__ H, const int* __restrict__ row_ptr,
        const int2* __restrict__ pairs, const float* __restrict__ dinv,
        const float* __restrict__ bias, const float* __restrict__ W,
        _Float16* __restrict__ Hout, int N) {
    __shared__ float pacc[16][64];
    __shared__ _Float16 sA[16][D2 + 8];
    const int tid = threadIdx.x;
    const int grp = tid >> 4;
    const int sub = (tid >> 3) & 1;
    const int sl  = tid & 7;
    const int node0 = blockIdx.x * 16;
    const int node = node0 + grp;
    const bool valid = node < N;

    float acc[8];
#pragma unroll
    for (int j = 0; j < 8; ++j) acc[j] = 0.0f;

    int beg = 0, end = 0;
    if (valid) { beg = row_ptr[node]; end = row_ptr[node + 1]; }

    const int kb = beg + sub;
    if (end > kb) {
        const int last = end - 1;
        int2 p0 = pairs[min(kb,     last)];
        int2 p1 = pairs[min(kb + 2, last)];
        int2 p2 = pairs[min(kb + 4, last)];
        int2 p3 = pairs[min(kb + 6, last)];
        int2 p4 = pairs[min(kb + 8, last)];
        half8 u0 = *(const half8*)&H[(size_t)p0.x * D2 + sl * 8];
        half8 u1 = *(const half8*)&H[(size_t)p1.x * D2 + sl * 8];
        half8 u2 = *(const half8*)&H[(size_t)p2.x * D2 + sl * 8];
        half8 u3 = *(const half8*)&H[(size_t)p3.x * D2 + sl * 8];
        for (int k = kb; k < end; k += 2) {
            int2 p5 = pairs[min(k + 10, last)];
            half8 u4 = *(const half8*)&H[(size_t)p4.x * D2 + sl * 8];
            float wv = __int_as_float(p0.y);
#pragma unroll
            for (int j = 0; j < 8; ++j) acc[j] = fmaf(wv, (float)u0[j], acc[j]);
            p0 = p1; p1 = p2; p2 = p3; p3 = p4; p4 = p5;
            u0 = u1; u1 = u2; u2 = u3; u3 = u4;
        }
    }
    if (valid && sub == 1) {
        *(float4*)&pacc[grp][sl * 8]     = make_float4(acc[0], acc[1], acc[2], acc[3]);
        *(float4*)&pacc[grp][sl * 8 + 4] = make_float4(acc[4], acc[5], acc[6], acc[7]);
    }
    __syncthreads();
    if (valid && sub == 0) {
        const float4 q0 = *(const float4*)&pacc[grp][sl * 8];
        const float4 q1 = *(const float4*)&pacc[grp][sl * 8 + 4];
        acc[0] += q0.x; acc[1] += q0.y; acc[2] += q0.z; acc[3] += q0.w;
        acc[4] += q1.x; acc[5] += q1.y; acc[6] += q1.z; acc[7] += q1.w;
        const float di = dinv[node];
        const float d2 = di * di;
        const half8 uself = *(const half8*)&H[(size_t)node * D2 + sl * 8];
#pragma unroll
        for (int j = 0; j < 8; ++j) acc[j] = fmaf(d2, (float)uself[j], acc[j]);
        float bb[8];
        *(float4*)&bb[0] = *(const float4*)&bias[sl * 8];
        *(float4*)&bb[4] = *(const float4*)&bias[sl * 8 + 4];
        half8 o;
#pragma unroll
        for (int j = 0; j < 8; ++j) o[j] = (_Float16)fmaxf(acc[j] + bb[j], 0.f);
        *(half8*)&sA[grp][sl * 8] = o;
    }
    __syncthreads();

    // gemm3 epilogue: 16 rows x K=64 @ W3(64x32); waves 0,1 (tile = wave)
    const int w = tid >> 6;
    const int lane = tid & 63;
    const int q = lane >> 4;
    const int m = lane & 15;
    if (w < 2) {
        half8 bf[2], a[2];
#pragma unroll
        for (int c = 0; c < 2; ++c) {
#pragma unroll
            for (int j = 0; j < 8; ++j)
                bf[c][j] = (_Float16)W[(size_t)(c * 32 + q * 8 + j) * D3 + w * 16 + m];
            a[c] = *(const half8*)&sA[m][c * 32 + q * 8];
        }
        floatx4 o4 = (floatx4){0.f, 0.f, 0.f, 0.f};
        o4 = __builtin_amdgcn_mfma_f32_16x16x32_f16(a[0], bf[0], o4, 0, 0, 0);
        o4 = __builtin_amdgcn_mfma_f32_16x16x32_f16(a[1], bf[1], o4, 0, 0, 0);
#pragma unroll
        for (int r = 0; r < 4; ++r) {
            const int nr = node0 + q * 4 + r;
            if (nr < N) Hout[(size_t)nr * D3 + w * 16 + m] = (_Float16)o4[r];
        }
    }
}

// ------------- layer-3 aggregate + epilogue, edge-split x4 (R21) -----------
// 16 threads/node: sub = bits2-3 (edge mod 4), sl = bits0-1 (4 cols x 8).
__global__ __launch_bounds__(256) void agg3_split_kernel(
        const _Float16* __restrict__ H, const int* __restrict__ row_ptr,
        const int2* __restrict__ pairs, const float* __restrict__ dinv,
        const float* __restrict__ bias, float* __restrict__ out, int N) {
    __shared__ float pacc[16][3][32];
    const int tid = threadIdx.x;
    const int grp = tid >> 4;
    const int sub = (tid >> 2) & 3;
    const int sl  = tid & 3;
    const int node = blockIdx.x * 16 + grp;
    const bool valid = node < N;

    float acc[8];
#pragma unroll
    for (int j = 0; j < 8; ++j) acc[j] = 0.0f;

    int beg = 0, end = 0;
    if (valid) { beg = row_ptr[node]; end = row_ptr[node + 1]; }

    const int kb = beg + sub;
    if (end > kb) {
        const int last = end - 1;
        int2 p0 = pairs[min(kb,      last)];
        int2 p1 = pairs[min(kb + 4,  last)];
        int2 p2 = pairs[min(kb + 8,  last)];
        int2 p3 = pairs[min(kb + 12, last)];
        int2 p4 = pairs[min(kb + 16, last)];
        half8 u0 = *(const half8*)&H[(size_t)p0.x * D3 + sl * 8];
        half8 u1 = *(const half8*)&H[(size_t)p1.x * D3 + sl * 8];
        half8 u2 = *(const half8*)&H[(size_t)p2.x * D3 + sl * 8];
        half8 u3 = *(const half8*)&H[(size_t)p3.x * D3 + sl * 8];
        for (int k = kb; k < end; k += 4) {
            int2 p5 = pairs[min(k + 20, last)];
            half8 u4 = *(const half8*)&H[(size_t)p4.x * D3 + sl * 8];
            float w = __int_as_float(p0.y);
#pragma unroll
            for (int j = 0; j < 8; ++j) acc[j] = fmaf(w, (float)u0[j], acc[j]);
            p0 = p1; p1 = p2; p2 = p3; p3 = p4; p4 = p5;
            u0 = u1; u1 = u2; u2 = u3; u3 = u4;
        }
    }
    if (valid && sub > 0) {
        *(float4*)&pacc[grp][sub - 1][sl * 8]     = make_float4(acc[0], acc[1], acc[2], acc[3]);
        *(float4*)&pacc[grp][sub - 1][sl * 8 + 4] = make_float4(acc[4], acc[5], acc[6], acc[7]);
    }
    __syncthreads();
    if (valid && sub == 0) {
#pragma unroll
        for (int s = 0; s < 3; ++s) {
            const float4 q0 = *(const float4*)&pacc[grp][s][sl * 8];
            const float4 q1 = *(const float4*)&pacc[grp][s][sl * 8 + 4];
            acc[0] += q0.x; acc[1] += q0.y; acc[2] += q0.z; acc[3] += q0.w;
            acc[4] += q1.x; acc[5] += q1.y; acc[6] += q1.z; acc[7] += q1.w;
        }
        const float di = dinv[node];
        const float d2 = di * di;
        const half8 uself = *(const half8*)&H[(size_t)node * D3 + sl * 8];
#pragma unroll
        for (int j = 0; j < 8; ++j) acc[j] = fmaf(d2, (float)uself[j], acc[j]);
        float bb[8];
        *(float4*)&bb[0] = *(const float4*)&bias[sl * 8];
        *(float4*)&bb[4] = *(const float4*)&bias[sl * 8 + 4];
#pragma unroll
        for (int j = 0; j < 8; ++j) acc[j] = fmaxf(acc[j] + bb[j], 0.f);
        float* dst = &out[(size_t)node * D3 + sl * 8];
        *(float4*)&dst[0] = make_float4(acc[0], acc[1], acc[2], acc[3]);
        *(float4*)&dst[4] = make_float4(acc[4], acc[5], acc[6], acc[7]);
    }
}

// ---------------------------------------------------------------- launch ----
extern "C" void kernel_launch(void* const* d_in, const int* in_sizes, int n_in,
                              void* d_out, int out_size, void* d_ws, size_t ws_size,
                              hipStream_t stream) {
    const float* x   = (const float*)d_in[0];
    const int* ei    = (const int*)d_in[1];
    const float* ew  = (const float*)d_in[2];
    const float* W1  = (const float*)d_in[3];
    const float* b1  = (const float*)d_in[4];
    const float* W2  = (const float*)d_in[5];
    const float* b2  = (const float*)d_in[6];
    const float* W3  = (const float*)d_in[7];
    const float* b3  = (const float*)d_in[8];
    float* out = (float*)d_out;

    const int N = in_sizes[0] / D0;   // 50000
    const int E = in_sizes[2];        // 800000
    (void)n_in; (void)out_size; (void)ws_size;

    // ---- workspace carving ----
    char* ws = (char*)d_ws;
    size_t off = 0;
    auto carve = [&](size_t bytes) -> void* {
        void* p = (void*)(ws + off);
        off += (bytes + 255) & ~(size_t)255;
        return p;
    };
    unsigned long long* pk = (unsigned long long*)carve((size_t)N * 8);
    float* dinv    = (float*)carve((size_t)N * 4);
    int*   cnt     = (int*)carve((size_t)N * 4);
    int*   row_ptr = (int*)carve((size_t)(N + 1) * 4);
    int*   rank    = (int*)carve((size_t)E * 4);
    int*   bsum    = (int*)carve(256 * 4);
    int2*  pairs   = (int2*)carve((size_t)E * 8);
    _Float16* bufH = (_Float16*)carve((size_t)N * D1 * 2);
    _Float16* bufO = (_Float16*)carve((size_t)N * D1 * 2);

    _Float16* h1 = bufH;              // N x 128 fp16 (gemm1 out)
    _Float16* h2 = bufO;              // N x 64  fp16 (agg1+gemm2 out)
    _Float16* h3 = bufH;              // N x 32  fp16 (agg2+gemm3 out; h1 dead)

    const int eb = (E + 255) / 256;       // 3125
    const int scanB = (N + 255) / 256;    // 196 (must be <= 256)
    const int gB = 768;                   // gemm1 blocks

    // ---- fused: hist + gemm1 (independent work, one dispatch) ----
    hipMemsetAsync(pk, 0, (size_t)N * 8, stream);
    hist_gemm1_kernel<<<gB + eb, 256, 0, stream>>>(
        x, W1, h1, N, ei, ew, pk, rank, E, gB);

    // ---- CSR scan ----
    scan_reduce<<<scanB, 256, 0, stream>>>(pk, dinv, cnt, bsum, N);
    scan_apply<<<scanB, 256, 0, stream>>>(cnt, bsum, row_ptr, N, scanB);

    // ---- CSR fill ----
    fill_kernel<<<eb, 256, 0, stream>>>(ei, ew, dinv, row_ptr, rank, pairs, E);

    // ---- layer 1 aggregate (+ fused gemm2: 128 -> 64) ----
    agg_gemm_kernel<D1, D2><<<(N + 15) / 16, 256, 0, stream>>>(
        h1, row_ptr, pairs, dinv, b1, W2, h2, N);

    // ---- layer 2 aggregate (+ fused gemm3: 64 -> 32), edge-split x2 ----
    agg2_split_kernel<<<(N + 15) / 16, 256, 0, stream>>>(
        h2, row_ptr, pairs, dinv, b2, W3, h3, N);

    // ---- layer 3 aggregate + epilogue (fp32 out), edge-split x4 ----
    agg3_split_kernel<<<(N + 15) / 16, 256, 0, stream>>>(
        h3, row_ptr, pairs, dinv, b3, out, N);
}